// Round 9
// baseline (33.129 us; speedup 1.0000x reference)
//
#include <hip/hip_runtime.h>
#include <stdint.h>

#define BB      512
#define NCROPS  5
#define TT      8192
#define THREADS 512
#define WAVES   8
#define HPAD    257   // 256 bins + 1 pad word -> cross-wave bank decorrelation

// Order-preserving f32 -> u32 transform (ascending).
// Every real float maps to a key > 0, so 0u is a safe "masked" sentinel.
__device__ __forceinline__ uint32_t f2ord(float f) {
    uint32_t b = __float_as_uint(f);
    return (b & 0x80000000u) ? ~b : (b | 0x80000000u);
}
__device__ __forceinline__ float ord2f(uint32_t u) {
    uint32_t b = (u & 0x80000000u) ? (u & 0x7FFFFFFFu) : ~u;
    return __uint_as_float(b);
}

// ---------------------------------------------------------------------------
// K1: streaming crop-mean + mask -> order keys. 4096 small blocks (512 rows x
// 8 chunks of 1024 elems), valid chunks only. High occupancy (no LDS, low
// VGPR), dynamic refill -> balanced, fill-kernel-like BW regime.
// ---------------------------------------------------------------------------
__global__ __launch_bounds__(256) void mean_keys(
    const float* __restrict__ scores, const int* __restrict__ seqlen,
    uint32_t* __restrict__ keys)
{
    const int bid = blockIdx.x;
    const int r   = bid >> 3;
    const int c   = bid & 7;
    const int sl  = seqlen[r];
    if (c * 1024 >= sl) return;                 // whole chunk invalid

    const int t4 = c * 256 + threadIdx.x;       // float4 index within row
    const int t0 = 4 * t4;
    if (t0 >= sl) return;                       // per-thread tail cut

    const float* base = scores + (size_t)r * NCROPS * TT;
    float4 a        = *reinterpret_cast<const float4*>(base + 0 * TT + t0);
    const float4 v1 = *reinterpret_cast<const float4*>(base + 1 * TT + t0);
    const float4 v2 = *reinterpret_cast<const float4*>(base + 2 * TT + t0);
    const float4 v3 = *reinterpret_cast<const float4*>(base + 3 * TT + t0);
    const float4 v4 = *reinterpret_cast<const float4*>(base + 4 * TT + t0);
    a.x = (a.x + v1.x + v2.x + v3.x + v4.x) * 0.2f;
    a.y = (a.y + v1.y + v2.y + v3.y + v4.y) * 0.2f;
    a.z = (a.z + v1.z + v2.z + v3.z + v4.z) * 0.2f;
    a.w = (a.w + v1.w + v2.w + v3.w + v4.w) * 0.2f;

    uint4 kv;
    kv.x = f2ord(a.x);                           // t0 < sl guaranteed
    kv.y = (t0 + 1 < sl) ? f2ord(a.y) : 0u;
    kv.z = (t0 + 2 < sl) ? f2ord(a.z) : 0u;
    kv.w = (t0 + 3 < sl) ? f2ord(a.w) : 0u;
    *reinterpret_cast<uint4*>(keys + (size_t)r * TT + t0) = kv;
}

// ---------------------------------------------------------------------------
// K2: per-row radix select + BCE term, reading the L2/L3-resident key buffer.
// Masked positions are synthesized as 0 in registers (never read from ws).
// ---------------------------------------------------------------------------
#define FOR4(OP) OP(u0) OP(u1) OP(u2) OP(u3)

__global__ __launch_bounds__(THREADS, 4) void select_loss(
    const uint32_t* __restrict__ keys, const int* __restrict__ label,
    const int* __restrict__ seqlen, float* __restrict__ row_loss)
{
    const int b    = blockIdx.x;
    const int tid  = threadIdx.x;
    const int lane = tid & 63;
    const int wave = tid >> 6;

    const int sl = seqlen[b];
    const int lb = label[b];
    const int k  = (lb == 0) ? 1 : (sl / 16 + 1);   // 1 <= k <= sl

    __shared__ uint32_t hist[2][WAVES][HPAD];       // ~16.4 KB, double-buffered
    __shared__ uint32_t bc_p, bc_k;
    __shared__ uint32_t s_m[WAVES];
    __shared__ float    s_s[WAVES];
    __shared__ int      s_c[WAVES];

    // ---- load keys (valid only; masked lanes = 0 sentinel) ----
    const uint32_t* kbase = keys + (size_t)b * TT;
    uint4 u0, u1, u2, u3;
    #define KLOADJ(DST, J) { \
        const int t4 = tid + (J) * THREADS; \
        if (4 * t4 < sl) DST = *reinterpret_cast<const uint4*>(kbase + 4 * t4); \
        else { DST.x = 0u; DST.y = 0u; DST.z = 0u; DST.w = 0u; } }
    KLOADJ(u0, 0)
    KLOADJ(u1, 1)
    KLOADJ(u2, 2)
    KLOADJ(u3, 3)

    // zero histogram buffer 0 while key loads are in flight
    {
        uint32_t* hz = &hist[0][0][0];
        for (int i = tid; i < WAVES * HPAD; i += THREADS) hz[i] = 0u;
    }
    __syncthreads();

    uint32_t thr;
    if (k == 1) {
        // ---- label==0 fast path: threshold = row max ----
        uint32_t mx = 0u;
        #define MAXOP(V) mx = max(mx, max(max(V.x, V.y), max(V.z, V.w)));
        FOR4(MAXOP)
        #pragma unroll
        for (int off = 32; off; off >>= 1) {
            const uint32_t o = (uint32_t)__shfl_down((int)mx, off);
            mx = max(mx, o);
        }
        if (lane == 0) s_m[wave] = mx;
        __syncthreads();
        uint32_t rowmax = s_m[0];
        #pragma unroll
        for (int w = 1; w < WAVES; ++w) rowmax = max(rowmax, s_m[w]);
        thr = rowmax;
    } else {
        // ---- MSB-first radix select, 4 rounds x 8 bits ----
        uint32_t p = 0u, kr = (uint32_t)k;
        #pragma unroll
        for (int r = 0; r < 4; ++r) {
            uint32_t* h = &hist[r & 1][wave][0];
            if (r == 0) {
                #define H0(X)  if ((X) != 0u) atomicAdd(&h[(X) >> 24], 1u);
                #define H0V(V) H0(V.x) H0(V.y) H0(V.z) H0(V.w)
                FOR4(H0V)
            } else {
                const int shp = 32 - 8 * r;   // prefix shift
                const int shd = shp - 8;      // digit shift
                #define HR(X)  if ((X) != 0u && ((X) >> shp) == p) atomicAdd(&h[((X) >> shd) & 255u], 1u);
                #define HRV(V) HR(V.x) HR(V.y) HR(V.z) HR(V.w)
                FOR4(HRV)
            }
            __syncthreads();
            if (wave == 0) {
                // combine 8 wave-hists (4 bins/lane), suffix-scan, pick digit
                uint32_t t0s = 0u, t1s = 0u, t2s = 0u, t3s = 0u;
                #pragma unroll
                for (int w = 0; w < WAVES; ++w) {
                    const uint32_t* hw = &hist[r & 1][w][0];
                    t0s += hw[4 * lane + 0];
                    t1s += hw[4 * lane + 1];
                    t2s += hw[4 * lane + 2];
                    t3s += hw[4 * lane + 3];
                }
                const uint32_t s = t0s + t1s + t2s + t3s;
                uint32_t suf = s;                         // inclusive suffix sum
                #pragma unroll
                for (int off = 1; off < 64; off <<= 1) {
                    const uint32_t v = (uint32_t)__shfl_down((int)suf, off);
                    if (lane + off < 64) suf += v;
                }
                const uint32_t E  = suf - s;              // sum over lanes > l
                const uint32_t T3 = E  + t3s;             // T(c) = cnt(keys >= bin c)
                const uint32_t T2 = T3 + t2s;
                const uint32_t T1 = T2 + t1s;
                const uint32_t T0 = T1 + t0s;
                const unsigned long long bal = __ballot(T0 >= kr);
                const int L = 63 - __clzll(bal);          // highest lane with T0 >= kr
                if (lane == L) {
                    uint32_t j, Tj, tj;
                    if      (T3 >= kr) { j = 3u; Tj = T3; tj = t3s; }
                    else if (T2 >= kr) { j = 2u; Tj = T2; tj = t2s; }
                    else if (T1 >= kr) { j = 1u; Tj = T1; tj = t1s; }
                    else               { j = 0u; Tj = T0; tj = t0s; }
                    bc_p = (p << 8) | (uint32_t)(4 * lane) | j;
                    bc_k = kr - (Tj - tj);                // rank within chosen bin
                }
            } else if (r < 3) {
                // zero the other buffer for the next round (overlaps the scan)
                uint32_t* hz = &hist[(r + 1) & 1][0][0];
                for (int i = tid - 64; i < WAVES * HPAD; i += (THREADS - 64)) hz[i] = 0u;
            }
            __syncthreads();
            p  = bc_p;
            kr = bc_k;
        }
        thr = p;   // exact bit pattern of the k-th largest key
    }

    // ---- unified epilogue: topk = sum(u>=thr) - (cnt(u>=thr)-k)*val(thr) ----
    float sg = 0.f;
    int   cg = 0;
    #define SUMOP(V) \
        if (V.x >= thr) { sg += ord2f(V.x); cg++; } \
        if (V.y >= thr) { sg += ord2f(V.y); cg++; } \
        if (V.z >= thr) { sg += ord2f(V.z); cg++; } \
        if (V.w >= thr) { sg += ord2f(V.w); cg++; }
    FOR4(SUMOP)
    #pragma unroll
    for (int off = 32; off; off >>= 1) {
        sg += __shfl_down(sg, off);
        cg += __shfl_down(cg, off);
    }
    if (lane == 0) { s_s[wave] = sg; s_c[wave] = cg; }
    __syncthreads();

    if (tid == 0) {
        float S = 0.f; int C = 0;
        #pragma unroll
        for (int w = 0; w < WAVES; ++w) { S += s_s[w]; C += s_c[w]; }
        const float kf   = ord2f(thr);
        const float topk = S - (float)(C - k) * kf;
        const float v    = topk / (float)k;
        const float y    = (float)lb;
        const float la   = fmaxf(v, 0.f) + log1pf(expf(-fabsf(v)));  // logaddexp(0,v)
        row_loss[b] = la - v * y;
    }
}

__global__ __launch_bounds__(256) void reduce_loss(
    const float* __restrict__ row_loss, float* __restrict__ out)
{
    const int tid = threadIdx.x;
    float v = row_loss[tid] + row_loss[tid + 256];
    #pragma unroll
    for (int off = 32; off; off >>= 1) v += __shfl_down(v, off);
    __shared__ float s[4];
    if ((tid & 63) == 0) s[tid >> 6] = v;
    __syncthreads();
    if (tid == 0) out[0] = (s[0] + s[1] + s[2] + s[3]) * (1.0f / 512.0f);
}

extern "C" void kernel_launch(void* const* d_in, const int* in_sizes, int n_in,
                              void* d_out, int out_size, void* d_ws, size_t ws_size,
                              hipStream_t stream) {
    const float* scores = (const float*)d_in[0];
    const int*   label  = (const int*)d_in[1];
    const int*   seqlen = (const int*)d_in[2];
    float* out = (float*)d_out;

    const size_t keys_bytes = (size_t)BB * TT * sizeof(uint32_t);   // 16.8 MB
    uint32_t* keys     = (uint32_t*)d_ws;
    float*    row_loss = (float*)((char*)d_ws + keys_bytes);        // 512 floats

    mean_keys<<<BB * 8, 256, 0, stream>>>(scores, seqlen, keys);
    select_loss<<<BB, THREADS, 0, stream>>>(keys, label, seqlen, row_loss);
    reduce_loss<<<1, 256, 0, stream>>>(row_loss, out);
}